// Round 1
// baseline (578.374 us; speedup 1.0000x reference)
//
#include <hip/hip_runtime.h>
#include <hip/hip_bf16.h>
#include <math.h>

#define TOKENS 8192
#define IN_F   4096
#define OUT_F  4096
#define LR     16

typedef __bf16 bf16_t;
typedef __attribute__((ext_vector_type(8)))  __bf16 bf16x8;
typedef __attribute__((ext_vector_type(4)))  __bf16 bf16x4;
typedef __attribute__((ext_vector_type(4)))  float  floatx4;
typedef __attribute__((ext_vector_type(16))) float  floatx16;

#define GL2LDS(gp, lp) \
    __builtin_amdgcn_global_load_lds((const __attribute__((address_space(1))) unsigned int*)(gp), \
                                     (__attribute__((address_space(3))) unsigned int*)(lp), 16, 0, 0)

// ---------------- kernel 1: P = A A^T (16x16), Q = B^T B (16x16) ----------------
__global__ void pq_kernel(const float* __restrict__ A, const float* __restrict__ B,
                          float* __restrict__ P, float* __restrict__ Q) {
    __shared__ float red[256];
    const int b = blockIdx.x, t = threadIdx.x;
    float s = 0.f;
    if (b < 256) {
        const int i = b >> 4, j = b & 15;
        const float* ai = A + (size_t)i * IN_F;
        const float* aj = A + (size_t)j * IN_F;
        for (int k = t; k < IN_F; k += 256) s += ai[k] * aj[k];
    } else {
        const int i = (b - 256) >> 4, j = (b - 256) & 15;
        for (int k = t; k < OUT_F; k += 256) s += B[k * LR + i] * B[k * LR + j];
    }
    red[t] = s; __syncthreads();
    for (int off = 128; off > 0; off >>= 1) {
        if (t < off) red[t] += red[t + off];
        __syncthreads();
    }
    if (t == 0) {
        if (b < 256) P[b] = red[0];
        else         Q[b - 256] = red[0];
    }
}

// ---------------- kernel 2: rank-space Newton-Schulz (fp64, 16x16) ----------------
__global__ void ns_kernel(const float* __restrict__ P, const float* __restrict__ Q,
                          float* __restrict__ Sc) {
    __shared__ double Ps[256], Qs[256], Ss[256], Ys[256], Zs[256], Ts[256], Us[256], Vs[256];
    __shared__ double alpha_s, inv_n;
    const int t = threadIdx.x, i = t >> 4, j = t & 15;
    Ps[t] = P[t]; Qs[t] = Q[t];
    __syncthreads();
    if (t == 0) {
        double s = 0.0;
        for (int a = 0; a < 16; ++a)
            for (int b2 = 0; b2 < 16; ++b2) s += Ps[a * 16 + b2] * Qs[b2 * 16 + a];
        const double al = sqrt(s);           // ||G||_F = sqrt(tr(P Q))
        alpha_s = al;
        inv_n   = 1.0 / (al + 1e-7);
    }
    __syncthreads();
    Ss[t] = (i == j) ? inv_n : 0.0;          // S_0 = I / (||G|| + eps)
    __syncthreads();
    const double ca = 3.4445, cb = -4.775, cc = 2.0315;
    for (int step = 0; step < 5; ++step) {
        double s;
        s = 0; for (int q = 0; q < 16; ++q) s += Ss[i*16+q] * Ps[q*16+j]; Ys[t] = s; __syncthreads(); // Y = S P
        s = 0; for (int q = 0; q < 16; ++q) s += Ys[i*16+q] * Ss[j*16+q]; Zs[t] = s; __syncthreads(); // Z = Y S^T
        s = 0; for (int q = 0; q < 16; ++q) s += Zs[i*16+q] * Qs[q*16+j]; Ts[t] = s; __syncthreads(); // T = Z Q
        s = 0; for (int q = 0; q < 16; ++q) s += Ts[i*16+q] * Ss[q*16+j]; Us[t] = s; __syncthreads(); // U = T S
        s = 0; for (int q = 0; q < 16; ++q) s += Ts[i*16+q] * Us[q*16+j]; Vs[t] = s; __syncthreads(); // V = T U
        Ss[t] = ca * Ss[t] + cb * Us[t] + cc * Vs[t];
        __syncthreads();
    }
    Sc[t] = (float)(alpha_s * Ss[t]);
}

// ---------------- kernel 3: ScA[r][i] = sum_q Sc[r][q] * A[q][i]  (16 x 4096) ----------------
__global__ void sca_kernel(const float* __restrict__ Sc, const float* __restrict__ A,
                           float* __restrict__ ScA) {
    const int idx = blockIdx.x * 256 + threadIdx.x;   // 65536 total
    const int r = idx >> 12, i = idx & 4095;
    float s = 0.f;
    for (int q = 0; q < 16; ++q) s += Sc[r * 16 + q] * A[q * IN_F + i];
    ScA[r * IN_F + i] = s;
}

// ---------------- kernel 4 (fused): x->bf16 convert  +  W_eff = W + B@ScA (bf16) ----
__global__ void prep_kernel(const float* __restrict__ x, bf16_t* __restrict__ Xb,
                            const float* __restrict__ W, const float* __restrict__ Bm,
                            const float* __restrict__ ScA, bf16_t* __restrict__ Wb) {
    const int b = blockIdx.x, t = threadIdx.x;
    if (b < 32768) {
        const int idx = b * 256 + t;                  // float4 index
        const float4 u = ((const float4*)x)[idx];
        bf16x4 v;
        v[0] = (__bf16)u.x; v[1] = (__bf16)u.y; v[2] = (__bf16)u.z; v[3] = (__bf16)u.w;
        ((bf16x4*)Xb)[idx] = v;
        return;
    }
    const int bb = b - 32768;
    const int o0 = (bb >> 2) * 4;             // 4 output rows per block
    const int i  = (bb & 3) * 1024 + t * 4;   // 4 consecutive cols per thread
    float4 acc[4];
    #pragma unroll
    for (int r = 0; r < 4; ++r) acc[r] = *(const float4*)&W[(size_t)(o0 + r) * IN_F + i];
    #pragma unroll
    for (int q = 0; q < LR; ++q) {
        const float4 sa = *(const float4*)&ScA[q * IN_F + i];
        #pragma unroll
        for (int r = 0; r < 4; ++r) {
            const float bq = Bm[(o0 + r) * LR + q];
            acc[r].x += bq * sa.x; acc[r].y += bq * sa.y;
            acc[r].z += bq * sa.z; acc[r].w += bq * sa.w;
        }
    }
    #pragma unroll
    for (int r = 0; r < 4; ++r) {
        bf16x4 v;
        v[0] = (__bf16)acc[r].x; v[1] = (__bf16)acc[r].y;
        v[2] = (__bf16)acc[r].z; v[3] = (__bf16)acc[r].w;
        *(bf16x4*)&Wb[(size_t)(o0 + r) * IN_F + i] = v;
    }
}

// ---------------- kernel 5: C = Xb @ Wb^T + bias  (256x256 tile, BK=32) ----------
// Round-5: 3-deep LDS ring (96 KB) -> provably race-free COUNTED vmcnt(4)
// pipeline (T3+T4), pair-packed XOR-swizzled LDS (T2), setprio (T5),
// XCD-bijective block swizzle (T1).
//
// LDS tile layout (A and B each 16 KB): logical (r,k), r in [0,256),
// k in [0,32).  lrow=r>>1, slot=((r&1)<<2)|(k>>3), phys slot'=slot^(lrow&7),
// byte = lrow*128 + slot'*16 + (k&7)*2.  Rows pair-packed into 128-B lines
// so a wave's 64 16B ds_reads spread 8-per-slot over all 8 chunk slots
// (bank-uniform).  global_load_lds writes LINEARLY (chunk g=j*512+t at byte
// g*16); the global SOURCE is inverse-swizzled (both-sides rule, m231).
//
// Pipeline invariant (wave-local vmcnt, barrier publishes cross-wave):
//   iter kt: read buf[kt%3], issue tile kt+2 (4 gl_lds) into buf[(kt+2)%3]
//   (that buf's last reads completed before iter kt-1's trailing barrier).
//   Trailing vmcnt(4): only tile kt+2's 4 ops may remain -> tile kt+1 is
//   complete in every wave before the barrier releases iter kt+1's reads.
#define GBM 256
#define GBN 256
#define GBK 32
#define GNT (IN_F / GBK)       // 128 k-tiles

__global__ __launch_bounds__(512, 2) void gemm_kernel(
        const bf16_t* __restrict__ Xb, const bf16_t* __restrict__ Wb,
        const float* __restrict__ bias, float* __restrict__ out) {
    __shared__ bf16_t lds[3 * 16384];    // 3 ring slots x (A 8192 + B 8192) elems = 96 KB
    const int t = threadIdx.x;
    const int lane = t & 63, wv = t >> 6;
    const int wm = wv & 1, wn = wv >> 1;          // 2x4 wave grid, 128x64 per wave
    const int ln = lane & 31, kg = lane >> 5;

    // T1: bijective XCD swizzle (512 blocks, 512 % 8 == 0), then column-major
    // tiles: 32 consecutive swz share one 2 MB Wb panel (fits XCD L2).
    const int bid = blockIdx.x;
    const int swz = (bid & 7) * 64 + (bid >> 3);
    const int mt = swz & 31, nt = swz >> 5;       // 32 x 16 tiles
    const int m0 = mt * GBM, n0 = nt * GBN;

    // staging source (inverse-swizzled): chunk g=j*512+t -> lrow=g>>3, sp=g&7,
    // slot=sp^(lrow&7), r=(lrow<<1)|(slot>>2), k0=(slot&3)*8.  j=1 is r+128.
    const int g_lrow = t >> 3, g_sp = t & 7;
    const int g_sl = g_sp ^ (g_lrow & 7);
    const int g_r  = (g_lrow << 1) | (g_sl >> 2);
    const int g_k0 = (g_sl & 3) * 8;
    const bf16_t* srcA0 = Xb + (size_t)(m0 + g_r) * IN_F + g_k0;
    const bf16_t* srcA1 = srcA0 + (size_t)128 * IN_F;
    const bf16_t* srcB0 = Wb + (size_t)(n0 + g_r) * IN_F + g_k0;
    const bf16_t* srcB1 = srcB0 + (size_t)128 * IN_F;
    const int dA0 = t * 8, dA1 = 4096 + t * 8;    // linear LDS dest (elements)

#define STAGE(buf, kt) do { \
        GL2LDS(srcA0 + (size_t)(kt) * GBK, (buf) + dA0); \
        GL2LDS(srcA1 + (size_t)(kt) * GBK, (buf) + dA1); \
        GL2LDS(srcB0 + (size_t)(kt) * GBK, (buf) + 8192 + dA0); \
        GL2LDS(srcB1 + (size_t)(kt) * GBK, (buf) + 8192 + dA1); \
    } while (0)

    // fragment read offsets: r = base + ln, k = s*16 + kg*8 + e.
    // lrow = base/2 + (ln>>1); slot' = (((ln&1)<<2)|(s*2+kg)) ^ ((ln>>1)&7).
    const int rx  = (ln >> 1) & 7;
    const int sl0 = ((((ln & 1) << 2) | kg)       ^ rx) * 8;
    const int sl1 = ((((ln & 1) << 2) | (2 + kg)) ^ rx) * 8;
    const int aRow = (wm * 64 + (ln >> 1)) * 64;          // + mf*1024
    const int bRow = 8192 + (wn * 32 + (ln >> 1)) * 64;   // + nf*1024

    floatx16 acc[4][2];
    #pragma unroll
    for (int mf = 0; mf < 4; ++mf)
        #pragma unroll
        for (int nf = 0; nf < 2; ++nf)
            acc[mf][nf] = (floatx16)(0.0f);

    bf16_t* bc = &lds[0];         // current compute buffer
    bf16_t* bn = &lds[16384];     // next (tile kt+1, in flight or landed)
    bf16_t* bs = &lds[32768];     // staging target (tile kt+2)

    // prologue: tiles 0,1 in flight; wait tile 0 (4 newest = tile 1 may fly)
    STAGE(bc, 0);
    STAGE(bn, 1);
    asm volatile("s_waitcnt vmcnt(4)" ::: "memory");
    __builtin_amdgcn_s_barrier();
    asm volatile("" ::: "memory");

    for (int kt = 0; kt < GNT; ++kt) {
        if (kt + 2 < GNT) STAGE(bs, kt + 2);      // into buf freed at iter kt-1

        bf16x8 a0[4], a1[4], b0[2], b1[2];
        #pragma unroll
        for (int mf = 0; mf < 4; ++mf) {
            a0[mf] = *(const bf16x8*)&bc[aRow + mf * 1024 + sl0];
            a1[mf] = *(const bf16x8*)&bc[aRow + mf * 1024 + sl1];
        }
        #pragma unroll
        for (int nf = 0; nf < 2; ++nf) {
            b0[nf] = *(const bf16x8*)&bc[bRow + nf * 1024 + sl0];
            b1[nf] = *(const bf16x8*)&bc[bRow + nf * 1024 + sl1];
        }

        __builtin_amdgcn_s_barrier();             // phase-align (T3 rhythm)
        asm volatile("" ::: "memory");
        __builtin_amdgcn_s_setprio(1);            // T5
        #pragma unroll
        for (int mf = 0; mf < 4; ++mf)
            #pragma unroll
            for (int nf = 0; nf < 2; ++nf)
                acc[mf][nf] = __builtin_amdgcn_mfma_f32_32x32x16_bf16(a0[mf], b0[nf], acc[mf][nf], 0, 0, 0);
        #pragma unroll
        for (int mf = 0; mf < 4; ++mf)
            #pragma unroll
            for (int nf = 0; nf < 2; ++nf)
                acc[mf][nf] = __builtin_amdgcn_mfma_f32_32x32x16_bf16(a1[mf], b1[nf], acc[mf][nf], 0, 0, 0);
        __builtin_amdgcn_s_setprio(0);

        if (kt < GNT - 2) asm volatile("s_waitcnt vmcnt(4)" ::: "memory");  // T4: counted
        else              asm volatile("s_waitcnt vmcnt(0)" ::: "memory");  // tail drain
        __builtin_amdgcn_s_barrier();
        asm volatile("" ::: "memory");

        bf16_t* tmp = bc; bc = bn; bn = bs; bs = tmp;   // rotate ring
    }
#undef STAGE

    // C/D layout (m74/m101): col = lane&31, row = (reg&3) + 8*(reg>>2) + 4*kg
    const int colb = n0 + wn * 64 + ln;
    const int rowb = m0 + wm * 128 + 4 * kg;
    const float bv0 = bias[colb];
    const float bv1 = bias[colb + 32];
    #pragma unroll
    for (int mf = 0; mf < 4; ++mf) {
        #pragma unroll
        for (int rg = 0; rg < 16; ++rg) {
            const int row = rowb + mf * 32 + (rg & 3) + 8 * (rg >> 2);
            out[(size_t)row * OUT_F + colb]      = acc[mf][0][rg] + bv0;
            out[(size_t)row * OUT_F + colb + 32] = acc[mf][1][rg] + bv1;
        }
    }
}

extern "C" void kernel_launch(void* const* d_in, const int* in_sizes, int n_in,
                              void* d_out, int out_size, void* d_ws, size_t ws_size,
                              hipStream_t stream) {
    const float* x    = (const float*)d_in[0];
    const float* W    = (const float*)d_in[1];
    const float* bias = (const float*)d_in[2];
    const float* lA_  = (const float*)d_in[3];
    const float* lB_  = (const float*)d_in[4];
    float* out = (float*)d_out;

    // workspace layout (~101 MB)
    char* ws = (char*)d_ws;
    bf16_t* Xb  = (bf16_t*)ws;                               // 8192*4096*2 = 67108864
    bf16_t* Wb  = (bf16_t*)(ws + 67108864);                  // 4096*4096*2 = 33554432
    float*  ScA = (float*)(ws + 100663296);                  // 16*4096*4   = 262144
    float*  P   = (float*)(ws + 100925440);                  // 256 floats
    float*  Q   = P + 256;
    float*  Sc  = Q + 256;

    pq_kernel  <<<512, 256, 0, stream>>>(lA_, lB_, P, Q);
    ns_kernel  <<<1, 256, 0, stream>>>(P, Q, Sc);
    sca_kernel <<<256, 256, 0, stream>>>(Sc, lA_, ScA);
    prep_kernel<<<36864, 256, 0, stream>>>(x, Xb, W, lB_, ScA, Wb);
    gemm_kernel<<<512, 512, 0, stream>>>(Xb, Wb, bias, out);
}

// Round 2
// 527.166 us; speedup vs baseline: 1.0971x; 1.0971x over previous
//
#include <hip/hip_runtime.h>
#include <hip/hip_bf16.h>
#include <math.h>

#define TOKENS 8192
#define IN_F   4096
#define OUT_F  4096
#define LR     16

typedef __bf16 bf16_t;
typedef __attribute__((ext_vector_type(8)))  __bf16 bf16x8;
typedef __attribute__((ext_vector_type(4)))  __bf16 bf16x4;
typedef __attribute__((ext_vector_type(4)))  float  floatx4;
typedef __attribute__((ext_vector_type(16))) float  floatx16;

#define GL2LDS(gp, lp) \
    __builtin_amdgcn_global_load_lds((const __attribute__((address_space(1))) unsigned int*)(gp), \
                                     (__attribute__((address_space(3))) unsigned int*)(lp), 16, 0, 0)

// ---------------- kernel 1: P = A A^T (16x16), Q = B^T B (16x16) ----------------
__global__ void pq_kernel(const float* __restrict__ A, const float* __restrict__ B,
                          float* __restrict__ P, float* __restrict__ Q) {
    __shared__ float red[256];
    const int b = blockIdx.x, t = threadIdx.x;
    float s = 0.f;
    if (b < 256) {
        const int i = b >> 4, j = b & 15;
        const float* ai = A + (size_t)i * IN_F;
        const float* aj = A + (size_t)j * IN_F;
        for (int k = t; k < IN_F; k += 256) s += ai[k] * aj[k];
    } else {
        const int i = (b - 256) >> 4, j = (b - 256) & 15;
        for (int k = t; k < OUT_F; k += 256) s += B[k * LR + i] * B[k * LR + j];
    }
    red[t] = s; __syncthreads();
    for (int off = 128; off > 0; off >>= 1) {
        if (t < off) red[t] += red[t + off];
        __syncthreads();
    }
    if (t == 0) {
        if (b < 256) P[b] = red[0];
        else         Q[b - 256] = red[0];
    }
}

// ---------------- kernel 2: rank-space Newton-Schulz (fp64, 16x16) ----------------
__global__ void ns_kernel(const float* __restrict__ P, const float* __restrict__ Q,
                          float* __restrict__ Sc) {
    __shared__ double Ps[256], Qs[256], Ss[256], Ys[256], Zs[256], Ts[256], Us[256], Vs[256];
    __shared__ double alpha_s, inv_n;
    const int t = threadIdx.x, i = t >> 4, j = t & 15;
    Ps[t] = P[t]; Qs[t] = Q[t];
    __syncthreads();
    if (t == 0) {
        double s = 0.0;
        for (int a = 0; a < 16; ++a)
            for (int b2 = 0; b2 < 16; ++b2) s += Ps[a * 16 + b2] * Qs[b2 * 16 + a];
        const double al = sqrt(s);           // ||G||_F = sqrt(tr(P Q))
        alpha_s = al;
        inv_n   = 1.0 / (al + 1e-7);
    }
    __syncthreads();
    Ss[t] = (i == j) ? inv_n : 0.0;          // S_0 = I / (||G|| + eps)
    __syncthreads();
    const double ca = 3.4445, cb = -4.775, cc = 2.0315;
    for (int step = 0; step < 5; ++step) {
        double s;
        s = 0; for (int q = 0; q < 16; ++q) s += Ss[i*16+q] * Ps[q*16+j]; Ys[t] = s; __syncthreads(); // Y = S P
        s = 0; for (int q = 0; q < 16; ++q) s += Ys[i*16+q] * Ss[j*16+q]; Zs[t] = s; __syncthreads(); // Z = Y S^T
        s = 0; for (int q = 0; q < 16; ++q) s += Zs[i*16+q] * Qs[q*16+j]; Ts[t] = s; __syncthreads(); // T = Z Q
        s = 0; for (int q = 0; q < 16; ++q) s += Ts[i*16+q] * Ss[q*16+j]; Us[t] = s; __syncthreads(); // U = T S
        s = 0; for (int q = 0; q < 16; ++q) s += Ts[i*16+q] * Us[q*16+j]; Vs[t] = s; __syncthreads(); // V = T U
        Ss[t] = ca * Ss[t] + cb * Us[t] + cc * Vs[t];
        __syncthreads();
    }
    Sc[t] = (float)(alpha_s * Ss[t]);
}

// ---------------- kernel 3: ScA[r][i] = sum_q Sc[r][q] * A[q][i]  (16 x 4096) ----------------
__global__ void sca_kernel(const float* __restrict__ Sc, const float* __restrict__ A,
                           float* __restrict__ ScA) {
    const int idx = blockIdx.x * 256 + threadIdx.x;   // 65536 total
    const int r = idx >> 12, i = idx & 4095;
    float s = 0.f;
    for (int q = 0; q < 16; ++q) s += Sc[r * 16 + q] * A[q * IN_F + i];
    ScA[r * IN_F + i] = s;
}

// ---------------- kernel 4 (fused): x->bf16 convert  +  W_eff = W + B@ScA (bf16) ----
__global__ void prep_kernel(const float* __restrict__ x, bf16_t* __restrict__ Xb,
                            const float* __restrict__ W, const float* __restrict__ Bm,
                            const float* __restrict__ ScA, bf16_t* __restrict__ Wb) {
    const int b = blockIdx.x, t = threadIdx.x;
    if (b < 32768) {
        const int idx = b * 256 + t;                  // float4 index
        const float4 u = ((const float4*)x)[idx];
        bf16x4 v;
        v[0] = (__bf16)u.x; v[1] = (__bf16)u.y; v[2] = (__bf16)u.z; v[3] = (__bf16)u.w;
        ((bf16x4*)Xb)[idx] = v;
        return;
    }
    const int bb = b - 32768;
    const int o0 = (bb >> 2) * 4;             // 4 output rows per block
    const int i  = (bb & 3) * 1024 + t * 4;   // 4 consecutive cols per thread
    float4 acc[4];
    #pragma unroll
    for (int r = 0; r < 4; ++r) acc[r] = *(const float4*)&W[(size_t)(o0 + r) * IN_F + i];
    #pragma unroll
    for (int q = 0; q < LR; ++q) {
        const float4 sa = *(const float4*)&ScA[q * IN_F + i];
        #pragma unroll
        for (int r = 0; r < 4; ++r) {
            const float bq = Bm[(o0 + r) * LR + q];
            acc[r].x += bq * sa.x; acc[r].y += bq * sa.y;
            acc[r].z += bq * sa.z; acc[r].w += bq * sa.w;
        }
    }
    #pragma unroll
    for (int r = 0; r < 4; ++r) {
        bf16x4 v;
        v[0] = (__bf16)acc[r].x; v[1] = (__bf16)acc[r].y;
        v[2] = (__bf16)acc[r].z; v[3] = (__bf16)acc[r].w;
        *(bf16x4*)&Wb[(size_t)(o0 + r) * IN_F + i] = v;
    }
}

// ---------------- kernel 5: C = Xb @ Wb^T + bias  --------------------------------
// Round-5: 8-phase-per-iteration schedule (T3+T4 gate) ported to plain HIP.
//   256x256 tile, BK=64 as 2 K-halves of 32; 8 waves (2M x 4N), 128x64 per wave;
//   mfma_f32_16x16x32_bf16, acc[8][4] floatx4 = 128 VGPR.
// LDS = 2 dbuf x 2 K-half x (A,B) x [256][32] units of 16 KB = 128 KB, 1 blk/CU.
// Per phase: {4-8 ds_read_b128 + one 16KB half-unit prefetch (2 gl2lds)}
//   -> barrier -> setprio(1) + 16 MFMA + setprio(0) -> [vmcnt(4)] -> barrier.
// Counted vmcnt(4) twice per K-tile; never drains to 0 until the final K-tile.
// Issue schedule (unit issued at phase, first LDS-read):
//   B-kh0(kt+1) @ P0(kt)  read P0(kt+1)  (4 phases of flight)
//   A-kh0(kt+1) @ P1(kt)  read P0(kt+1)  (3)
//   B-kh1(kt+1) @ P2(kt)  read P2(kt+1)  (4)
//   A-kh1(kt+1) @ P3(kt)  read P2(kt+1)  (3)
// vmcnt(4) at P1-trailing guards {A-kh1(kt), B-kh1(kt)} (issues after them = 4);
// vmcnt(4) at P3-trailing guards {A-kh0(kt+1), B-kh0(kt+1)}.  All waves issue the
// same sequence, so per-wave vmcnt + barrier bounds every wave's outstanding
// loads to the 2 newest units -> cross-wave LDS readiness holds.
// T2 swizzle: unit rows have 4x16B chunks; phys chunk = c ^ ((r>>1)&3).
//   Frag-read bank-group = 4*(r&1) | phys_chunk -> each 16-lane quarter hits all
//   8 bank-groups exactly 2x (2-way = free, m136).  gl2lds dest stays LINEAR;
//   global SOURCE is inverse-swizzled (involution; both-sides rule m231).
#define GNT 64              // K-tiles of 64

#define FENCE asm volatile("" ::: "memory")
#define BAR   do { __builtin_amdgcn_s_barrier(); FENCE; } while (0)

// stage one 16KB half-unit: 512 threads x 2 chunks of 16B (rows j*128 + t>>2)
#define STG(ubase, srcp, koff) do { \
    GL2LDS((srcp) + (koff), &lds[(ubase) + t * 8]); \
    GL2LDS((srcp) + (size_t)128 * IN_F + (koff), &lds[(ubase) + 4096 + t * 8]); } while (0)

#define PH_A(KS, D, MH, af) do { \
    af[0] = *(const bf16x8*)&lds[aRd + ((KS)*2+(D))*8192 + ((MH)*4+0)*512]; \
    af[1] = *(const bf16x8*)&lds[aRd + ((KS)*2+(D))*8192 + ((MH)*4+1)*512]; \
    af[2] = *(const bf16x8*)&lds[aRd + ((KS)*2+(D))*8192 + ((MH)*4+2)*512]; \
    af[3] = *(const bf16x8*)&lds[aRd + ((KS)*2+(D))*8192 + ((MH)*4+3)*512]; } while (0)

#define PH_B(KS, D, bfv) do { \
    bfv[0] = *(const bf16x8*)&lds[bRd + ((KS)*2+(D))*8192 + 0*512]; \
    bfv[1] = *(const bf16x8*)&lds[bRd + ((KS)*2+(D))*8192 + 1*512]; \
    bfv[2] = *(const bf16x8*)&lds[bRd + ((KS)*2+(D))*8192 + 2*512]; \
    bfv[3] = *(const bf16x8*)&lds[bRd + ((KS)*2+(D))*8192 + 3*512]; } while (0)

#define MFMA16(MH, af, bfv) do { \
    _Pragma("unroll") \
    for (int _i = 0; _i < 4; ++_i) { \
        acc[(MH)*4+_i][0] = __builtin_amdgcn_mfma_f32_16x16x32_bf16(af[_i], bfv[0], acc[(MH)*4+_i][0], 0, 0, 0); \
        acc[(MH)*4+_i][1] = __builtin_amdgcn_mfma_f32_16x16x32_bf16(af[_i], bfv[1], acc[(MH)*4+_i][1], 0, 0, 0); \
        acc[(MH)*4+_i][2] = __builtin_amdgcn_mfma_f32_16x16x32_bf16(af[_i], bfv[2], acc[(MH)*4+_i][2], 0, 0, 0); \
        acc[(MH)*4+_i][3] = __builtin_amdgcn_mfma_f32_16x16x32_bf16(af[_i], bfv[3], acc[(MH)*4+_i][3], 0, 0, 0); \
    } } while (0)

// one K-tile = 4 phases.  D = dbuf of this K-tile, DN = 1-D, KTN = K-tile staged.
#define KTILE(D, DN, KTN, DO_STAGE, VMN_MID, DO_VM_END) do { \
    bf16x8 af[4]; bf16x8 bfv[4]; \
    /* P0: ks0/mh0 */ \
    PH_A(0, D, 0, af); PH_B(0, D, bfv); \
    if (DO_STAGE) STG(32768 + (DN)*8192, sB, (size_t)(KTN)*64); \
    BAR; \
    __builtin_amdgcn_s_setprio(1); MFMA16(0, af, bfv); __builtin_amdgcn_s_setprio(0); \
    BAR; \
    /* P1: ks0/mh1 */ \
    PH_A(0, D, 1, af); \
    if (DO_STAGE) STG((DN)*8192, sA, (size_t)(KTN)*64); \
    BAR; \
    __builtin_amdgcn_s_setprio(1); MFMA16(1, af, bfv); __builtin_amdgcn_s_setprio(0); \
    if ((VMN_MID) == 4) asm volatile("s_waitcnt vmcnt(4)" ::: "memory"); \
    else                asm volatile("s_waitcnt vmcnt(0)" ::: "memory"); \
    BAR; \
    /* P2: ks1/mh0 */ \
    PH_A(1, D, 0, af); PH_B(1, D, bfv); \
    if (DO_STAGE) STG(32768 + (2+(DN))*8192, sB, (size_t)(KTN)*64 + 32); \
    BAR; \
    __builtin_amdgcn_s_setprio(1); MFMA16(0, af, bfv); __builtin_amdgcn_s_setprio(0); \
    BAR; \
    /* P3: ks1/mh1 */ \
    PH_A(1, D, 1, af); \
    if (DO_STAGE) STG((2+(DN))*8192, sA, (size_t)(KTN)*64 + 32); \
    BAR; \
    __builtin_amdgcn_s_setprio(1); MFMA16(1, af, bfv); __builtin_amdgcn_s_setprio(0); \
    if (DO_VM_END) asm volatile("s_waitcnt vmcnt(4)" ::: "memory"); \
    BAR; \
} while (0)

__global__ __launch_bounds__(512, 2) void gemm_kernel(
        const bf16_t* __restrict__ Xb, const bf16_t* __restrict__ Wb,
        const float* __restrict__ bias, float* __restrict__ out) {
    __shared__ bf16_t lds[65536];   // 128 KB: A units [4][8192], then B units [4][8192]
    const int t = threadIdx.x;
    const int lane = t & 63, wv = t >> 6;
    const int wm = wv & 1, wn = wv >> 1;          // 2x4 wave grid, 128x64 per wave
    const int fl = lane & 15, q = lane >> 4;      // frag row/col, k-quarter

    // T1: bijective XCD swizzle (512 blocks % 8 == 0); XCD r owns nt in {2r,2r+1}
    // -> 4 MB Wb panel resident in its L2 while Xb streams from L3.
    const int bid = blockIdx.x;
    const int swz = (bid & 7) * 64 + (bid >> 3);
    const int mt = swz & 31, nt = swz >> 5;       // 32 x 16 tiles
    const int m0 = mt * 256, n0 = nt * 256;

    // ds_read bases (element indices).  Unit layout: elem = r*32 + pc*8 + e,
    // pc = c ^ ((r>>1)&3).  (r>>1)&3 depends only on fl (wm/wn/mf/nf shifts are
    // multiples of 8 rows) -> frag offsets fold to immediates.
    const int rx  = (fl >> 1) & 3;
    const int aRd = (wm * 128 + fl) * 32 + ((q ^ rx) << 3);
    const int bRd = 32768 + (wn * 64 + fl) * 32 + ((q ^ rx) << 3);

    // staging source (inverse-swizzled): chunk g = j*512+t -> row g>>2, phys
    // chunk g&3 holds logical chunk (g&3)^((g>>3)&3)  (j-independent).
    const int cS = (t & 3) ^ ((t >> 3) & 3);
    const int rS = t >> 2;
    const bf16_t* sA = Xb + (size_t)(m0 + rS) * IN_F + cS * 8;
    const bf16_t* sB = Wb + (size_t)(n0 + rS) * IN_F + cS * 8;

    floatx4 acc[8][4];
    #pragma unroll
    for (int i = 0; i < 8; ++i)
        #pragma unroll
        for (int n = 0; n < 4; ++n) acc[i][n] = (floatx4)(0.0f);

    // prologue: B-kh0(0), A-kh0(0), B-kh1(0), A-kh1(0); wait first two units
    STG(32768 + 0 * 8192, sB, 0);
    STG(0 * 8192,         sA, 0);
    STG(32768 + 2 * 8192, sB, 32);
    STG(2 * 8192,         sA, 32);
    asm volatile("s_waitcnt vmcnt(4)" ::: "memory");
    BAR;

    for (int kt2 = 0; kt2 < GNT / 2 - 1; ++kt2) {
        const int kt = kt2 * 2;
        KTILE(0, 1, kt + 1, true, 4, true);
        KTILE(1, 0, kt + 2, true, 4, true);
    }
    // last pair: kt = GNT-2 stages GNT-1 normally; kt = GNT-1 stages nothing,
    // drains with vmcnt(0) at its mid wait (guards A/B-kh1(GNT-1)).
    KTILE(0, 1, GNT - 1, true, 4, true);
    KTILE(1, 0, 0, false, 0, false);

    // C/D layout 16x16x32 (m89/m91): col = lane&15, row = (lane>>4)*4 + reg
    const int colb = n0 + wn * 64 + fl;
    const int rowb = m0 + wm * 128 + q * 4;
    float bvv[4];
    #pragma unroll
    for (int nf = 0; nf < 4; ++nf) bvv[nf] = bias[colb + nf * 16];
    #pragma unroll
    for (int mf = 0; mf < 8; ++mf) {
        #pragma unroll
        for (int rg = 0; rg < 4; ++rg) {
            const int row = rowb + mf * 16 + rg;
            #pragma unroll
            for (int nf = 0; nf < 4; ++nf)
                out[(size_t)row * OUT_F + colb + nf * 16] = acc[mf][nf][rg] + bvv[nf];
        }
    }
}

extern "C" void kernel_launch(void* const* d_in, const int* in_sizes, int n_in,
                              void* d_out, int out_size, void* d_ws, size_t ws_size,
                              hipStream_t stream) {
    const float* x    = (const float*)d_in[0];
    const float* W    = (const float*)d_in[1];
    const float* bias = (const float*)d_in[2];
    const float* lA_  = (const float*)d_in[3];
    const float* lB_  = (const float*)d_in[4];
    float* out = (float*)d_out;

    // workspace layout (~101 MB)
    char* ws = (char*)d_ws;
    bf16_t* Xb  = (bf16_t*)ws;                               // 8192*4096*2 = 67108864
    bf16_t* Wb  = (bf16_t*)(ws + 67108864);                  // 4096*4096*2 = 33554432
    float*  ScA = (float*)(ws + 100663296);                  // 16*4096*4   = 262144
    float*  P   = (float*)(ws + 100925440);                  // 256 floats
    float*  Q   = P + 256;
    float*  Sc  = Q + 256;

    pq_kernel  <<<512, 256, 0, stream>>>(lA_, lB_, P, Q);
    ns_kernel  <<<1, 256, 0, stream>>>(P, Q, Sc);
    sca_kernel <<<256, 256, 0, stream>>>(Sc, lA_, ScA);
    prep_kernel<<<36864, 256, 0, stream>>>(x, Xb, W, lB_, ScA, Wb);
    gemm_kernel<<<512, 512, 0, stream>>>(Xb, Wb, bias, out);
}